// Round 1
// baseline (216.323 us; speedup 1.0000x reference)
//
#include <hip/hip_runtime.h>

#define NN 16384
#define DD 512
#define HH 64
#define LL 7

// ws layout (floats):
// [0]        S = row.sum()
// [8..15)    c[7]   (atomic accum)
// [16..3600) g[7*512] (atomic accum)
// [4096..20480) para[N]
#define WS_S    0
#define WS_C    8
#define WS_G    16
#define WS_PARA 4096

__device__ __forceinline__ float block_reduce_sum(float v, float* sdata) {
    #pragma unroll
    for (int off = 32; off > 0; off >>= 1)
        v += __shfl_down(v, off);
    int lane = threadIdx.x & 63;
    int wid  = threadIdx.x >> 6;
    if (lane == 0) sdata[wid] = v;
    __syncthreads();
    int nw = blockDim.x >> 6;
    float s = (threadIdx.x < nw) ? sdata[threadIdx.x] : 0.f;
    if (threadIdx.x < 64) {
        #pragma unroll
        for (int off = 32; off > 0; off >>= 1)
            s += __shfl_down(s, off);
    }
    return s;  // valid in thread 0
}

// Kernel 1: S = sum(matrix[index, :])
__global__ void k_rowsum(const float* __restrict__ matrix,
                         const int* __restrict__ pidx,
                         float* __restrict__ wsf) {
    __shared__ float sdata[16];
    int idx = *pidx;
    const float* row = matrix + (size_t)idx * NN;
    float v = 0.f;
    for (int i = threadIdx.x * 4; i < NN; i += blockDim.x * 4) {
        float4 r = *(const float4*)(row + i);
        v += r.x + r.y + r.z + r.w;
    }
    float s = block_reduce_sum(v, sdata);
    if (threadIdx.x == 0) wsf[WS_S] = s;
}

// Kernel 2: para[j] = row_j / sqrt(deg_j * S); deg only computed for neighbors.
__global__ void k_para(const float* __restrict__ matrix,
                       const int* __restrict__ pidx,
                       const float* __restrict__ wsf,
                       float* __restrict__ para) {
    __shared__ float sdata[16];
    int j = blockIdx.x;
    int idx = *pidx;
    float r = matrix[(size_t)idx * NN + j];  // broadcast, L2-cached row
    if (r == 0.f) {
        if (threadIdx.x == 0) para[j] = 0.f;
        return;
    }
    const float* row = matrix + (size_t)j * NN;
    float v = 0.f;
    for (int i = threadIdx.x * 4; i < NN; i += blockDim.x * 4) {
        float4 t = *(const float4*)(row + i);
        v += t.x + t.y + t.z + t.w;
    }
    float deg = block_reduce_sum(v, sdata);
    if (threadIdx.x == 0) {
        float S = wsf[WS_S];
        para[j] = r * rsqrtf(deg * S);
    }
}

// Kernel 3: g[l][d] = sum_j para_j * lab[j][l] * x_f[j][d];  c[l] = sum_j para_j*lab[j][l]
__global__ void k_agg(const float* __restrict__ xf,
                      const int* __restrict__ lab,
                      const float* __restrict__ para,
                      float* __restrict__ g,
                      float* __restrict__ c) {
    int t = threadIdx.x;          // 256 threads, each owns 2 feature dims
    int d0 = t * 2;
    float2 acc[LL];
    #pragma unroll
    for (int l = 0; l < LL; ++l) acc[l] = make_float2(0.f, 0.f);
    float cacc[LL] = {0.f, 0.f, 0.f, 0.f, 0.f, 0.f, 0.f};
    for (int j = blockIdx.x; j < NN; j += gridDim.x) {
        float p = para[j];
        if (p == 0.f) continue;
        float w[LL];
        #pragma unroll
        for (int l = 0; l < LL; ++l) w[l] = p * (float)lab[j * LL + l];
        float2 xv = *(const float2*)(xf + (size_t)j * DD + d0);
        #pragma unroll
        for (int l = 0; l < LL; ++l) {
            acc[l].x = fmaf(w[l], xv.x, acc[l].x);
            acc[l].y = fmaf(w[l], xv.y, acc[l].y);
        }
        if (t == 0) {
            #pragma unroll
            for (int l = 0; l < LL; ++l) cacc[l] += w[l];
        }
    }
    #pragma unroll
    for (int l = 0; l < LL; ++l) {
        atomicAdd(&g[l * DD + d0],     acc[l].x);
        atomicAdd(&g[l * DD + d0 + 1], acc[l].y);
    }
    if (t == 0) {
        #pragma unroll
        for (int l = 0; l < LL; ++l) atomicAdd(&c[l], cacc[l]);
    }
}

// Kernel 4 (1 block, 512 threads): z[index], tmp_a = g@W2 + c*b2, relu, max, @Wp+bp
__global__ void k_final(const float* __restrict__ xf,
                        const float* __restrict__ W2,
                        const float* __restrict__ b2,
                        const float* __restrict__ Wp,
                        const float* __restrict__ bp,
                        const int* __restrict__ pidx,
                        const float* __restrict__ g,
                        const float* __restrict__ c,
                        float* __restrict__ out) {
    __shared__ float out_acc[LL];
    int t = threadIdx.x;  // 512
    int idx = *pidx;
    float val;
    if (t < HH) {
        // z[index][t] = x_f[index] @ W2[:,t] + b2[t]
        float s = b2[t];
        const float* xrow = xf + (size_t)idx * DD;
        #pragma unroll 4
        for (int d = 0; d < DD; ++d)
            s = fmaf(xrow[d], W2[d * HH + t], s);
        val = s;
    } else {
        // tmp_a[l][h] = g[l] @ W2[:,h] + c[l]*b2[h]; concat pos = 64 + l*64 + h = t
        int l = (t - HH) >> 6;
        int h = (t - HH) & 63;
        float s = c[l] * b2[h];
        const float* gl = g + l * DD;
        #pragma unroll 4
        for (int d = 0; d < DD; ++d)
            s = fmaf(gl[d], W2[d * HH + h], s);
        val = s;
    }
    float relu_v = val > 0.f ? val : 0.f;
    float h_combi = fmaxf(xf[(size_t)idx * DD + t], relu_v);

    if (t < LL) out_acc[t] = 0.f;
    __syncthreads();

    float p[LL];
    #pragma unroll
    for (int o = 0; o < LL; ++o) p[o] = h_combi * Wp[t * LL + o];
    #pragma unroll
    for (int o = 0; o < LL; ++o) {
        #pragma unroll
        for (int off = 32; off > 0; off >>= 1)
            p[o] += __shfl_down(p[o], off);
    }
    if ((t & 63) == 0) {
        #pragma unroll
        for (int o = 0; o < LL; ++o) atomicAdd(&out_acc[o], p[o]);
    }
    __syncthreads();
    if (t < LL) out[t] = out_acc[t] + bp[t];
}

extern "C" void kernel_launch(void* const* d_in, const int* in_sizes, int n_in,
                              void* d_out, int out_size, void* d_ws, size_t ws_size,
                              hipStream_t stream) {
    const float* matrix = (const float*)d_in[0];
    const float* xf     = (const float*)d_in[1];
    const float* W2     = (const float*)d_in[2];
    const float* b2     = (const float*)d_in[3];
    const float* Wp     = (const float*)d_in[4];
    const float* bp     = (const float*)d_in[5];
    const int*   lab    = (const int*)d_in[6];
    const int*   pidx   = (const int*)d_in[7];
    float* outp = (float*)d_out;
    float* wsf  = (float*)d_ws;

    // zero the atomic accumulators (S..g region); para is fully overwritten
    hipMemsetAsync(d_ws, 0, (WS_G + LL * DD) * sizeof(float), stream);

    k_rowsum<<<1, 256, 0, stream>>>(matrix, pidx, wsf);
    k_para<<<NN, 256, 0, stream>>>(matrix, pidx, wsf, wsf + WS_PARA);
    k_agg<<<256, 256, 0, stream>>>(xf, lab, wsf + WS_PARA, wsf + WS_G, wsf + WS_C);
    k_final<<<1, 512, 0, stream>>>(xf, W2, b2, Wp, bp, pidx,
                                   wsf + WS_G, wsf + WS_C, outp);
}

// Round 2
// 172.602 us; speedup vs baseline: 1.2533x; 1.2533x over previous
//
#include <hip/hip_runtime.h>

#define NN 16384
#define DD 512
#define HH 64
#define LL 7

// ws layout (floats):
// [0]          count (int) — number of neighbors == S (binary matrix)
// [8..15)      c'[7]   (atomic accum, excludes rsqrt(S) factor)
// [16..3600)   g'[7*512] (atomic accum, excludes rsqrt(S) factor)
// [4096..20480)  nbr[N] (int, compacted neighbor indices)
// [20480..36864) qv[N]  (float, rsqrt(deg) per compact slot)
#define WS_CNT  0
#define WS_C    8
#define WS_G    16
#define WS_NBR  4096
#define WS_QV   20480

__device__ __forceinline__ float block_reduce_sum_256(float v, float* sdata) {
    #pragma unroll
    for (int off = 32; off > 0; off >>= 1)
        v += __shfl_down(v, off);
    int lane = threadIdx.x & 63;
    int wid  = threadIdx.x >> 6;
    if (lane == 0) sdata[wid] = v;
    __syncthreads();
    float s = (threadIdx.x < 4) ? sdata[threadIdx.x] : 0.f;
    if (threadIdx.x < 64) {
        s += __shfl_down(s, 2);
        s += __shfl_down(s, 1);
    }
    return s;  // valid in thread 0
}

// Kernel 1: compact neighbor indices of row `index`; count doubles as S.
__global__ void k_prep(const float* __restrict__ matrix,
                       const int* __restrict__ pidx,
                       int* __restrict__ count,
                       int* __restrict__ nbr) {
    int j = blockIdx.x * blockDim.x + threadIdx.x;   // 64 blocks * 256 = 16384
    int idx = *pidx;
    float r = matrix[(size_t)idx * NN + j];
    bool pred = (r != 0.f);
    unsigned long long mask = __ballot(pred);
    int lane = threadIdx.x & 63;
    int base = 0;
    if (lane == 0) base = atomicAdd(count, __popcll(mask));
    base = __shfl(base, 0);
    if (pred) {
        int off = __popcll(mask & ((1ull << lane) - 1ull));
        nbr[base + off] = j;
    }
}

// Kernel 2: per compacted neighbor row j, qv[i] = rsqrt(deg_j). Dense blocks.
__global__ void k_deg(const float* __restrict__ matrix,
                      const int* __restrict__ count,
                      const int* __restrict__ nbr,
                      float* __restrict__ qv) {
    __shared__ float sdata[4];
    int t = threadIdx.x;
    int cnt = *count;
    for (int i = blockIdx.x; i < cnt; i += gridDim.x) {
        int j = nbr[i];
        const float4* r4 = (const float4*)(matrix + (size_t)j * NN);
        // 4096 float4s over 256 threads = 16 loads/thread; 4 accumulators for ILP
        float v0 = 0.f, v1 = 0.f, v2 = 0.f, v3 = 0.f;
        #pragma unroll
        for (int it = 0; it < 4; ++it) {
            float4 a = r4[t + (it * 4 + 0) * 256];
            float4 b = r4[t + (it * 4 + 1) * 256];
            float4 cc = r4[t + (it * 4 + 2) * 256];
            float4 d = r4[t + (it * 4 + 3) * 256];
            v0 += a.x + a.y + a.z + a.w;
            v1 += b.x + b.y + b.z + b.w;
            v2 += cc.x + cc.y + cc.z + cc.w;
            v3 += d.x + d.y + d.z + d.w;
        }
        float deg = block_reduce_sum_256(v0 + v1 + v2 + v3, sdata);
        if (t == 0) qv[i] = rsqrtf(deg);
        if (gridDim.x <= cnt) __syncthreads();  // reuse sdata safely on 2nd trip
    }
}

// Kernel 3: g'[l][d] = sum_i q_i * lab[j_i][l] * xf[j_i][d];  c'[l] = sum_i q_i*lab[j_i][l]
__global__ void k_agg(const float* __restrict__ xf,
                      const int* __restrict__ lab,
                      const int* __restrict__ count,
                      const int* __restrict__ nbr,
                      const float* __restrict__ qv,
                      float* __restrict__ g,
                      float* __restrict__ c) {
    int t = threadIdx.x;          // 256 threads, each owns 2 feature dims
    int d0 = t * 2;
    int cnt = *count;
    float2 acc[LL];
    #pragma unroll
    for (int l = 0; l < LL; ++l) acc[l] = make_float2(0.f, 0.f);
    float cacc[LL] = {0.f, 0.f, 0.f, 0.f, 0.f, 0.f, 0.f};
    for (int i = blockIdx.x; i < cnt; i += gridDim.x) {
        int j = nbr[i];
        float q = qv[i];
        float w[LL];
        #pragma unroll
        for (int l = 0; l < LL; ++l) w[l] = q * (float)lab[j * LL + l];
        float2 xv = *(const float2*)(xf + (size_t)j * DD + d0);
        #pragma unroll
        for (int l = 0; l < LL; ++l) {
            acc[l].x = fmaf(w[l], xv.x, acc[l].x);
            acc[l].y = fmaf(w[l], xv.y, acc[l].y);
        }
        if (t == 0) {
            #pragma unroll
            for (int l = 0; l < LL; ++l) cacc[l] += w[l];
        }
    }
    #pragma unroll
    for (int l = 0; l < LL; ++l) {
        atomicAdd(&g[l * DD + d0],     acc[l].x);
        atomicAdd(&g[l * DD + d0 + 1], acc[l].y);
    }
    if (t == 0) {
        #pragma unroll
        for (int l = 0; l < LL; ++l) atomicAdd(&c[l], cacc[l]);
    }
}

// Kernel 4 (1 block, 512 threads): z[index], tmp_a = rsqrt(S)*(g'@W2 + c'*b2),
// relu, concat, elementwise-max with xf[index], @Wp + bp.
__global__ void k_final(const float* __restrict__ xf,
                        const float* __restrict__ W2,
                        const float* __restrict__ b2,
                        const float* __restrict__ Wp,
                        const float* __restrict__ bp,
                        const int* __restrict__ pidx,
                        const int* __restrict__ count,
                        const float* __restrict__ g,
                        const float* __restrict__ c,
                        float* __restrict__ out) {
    __shared__ float out_acc[LL];
    int t = threadIdx.x;  // 512
    int idx = *pidx;
    float sc = rsqrtf((float)(*count));
    const float* src;
    float bias;
    int h;
    if (t < HH) {
        src = xf + (size_t)idx * DD;   // z[index][t]
        h = t;
        bias = b2[t];
    } else {
        int l = (t - HH) >> 6;
        h = (t - HH) & 63;
        src = g + l * DD;
        bias = c[l] * b2[h];
    }
    float s0 = 0.f, s1 = 0.f, s2 = 0.f, s3 = 0.f;
    #pragma unroll 4
    for (int d = 0; d < DD; d += 4) {
        s0 = fmaf(src[d],     W2[(d)     * HH + h], s0);
        s1 = fmaf(src[d + 1], W2[(d + 1) * HH + h], s1);
        s2 = fmaf(src[d + 2], W2[(d + 2) * HH + h], s2);
        s3 = fmaf(src[d + 3], W2[(d + 3) * HH + h], s3);
    }
    float val = (s0 + s1) + (s2 + s3) + bias;
    if (t >= HH) val *= sc;
    float relu_v = val > 0.f ? val : 0.f;
    float h_combi = fmaxf(xf[(size_t)idx * DD + t], relu_v);

    if (t < LL) out_acc[t] = 0.f;
    __syncthreads();

    float p[LL];
    #pragma unroll
    for (int o = 0; o < LL; ++o) p[o] = h_combi * Wp[t * LL + o];
    #pragma unroll
    for (int o = 0; o < LL; ++o) {
        #pragma unroll
        for (int off = 32; off > 0; off >>= 1)
            p[o] += __shfl_down(p[o], off);
    }
    if ((t & 63) == 0) {
        #pragma unroll
        for (int o = 0; o < LL; ++o) atomicAdd(&out_acc[o], p[o]);
    }
    __syncthreads();
    if (t < LL) out[t] = out_acc[t] + bp[t];
}

extern "C" void kernel_launch(void* const* d_in, const int* in_sizes, int n_in,
                              void* d_out, int out_size, void* d_ws, size_t ws_size,
                              hipStream_t stream) {
    const float* matrix = (const float*)d_in[0];
    const float* xf     = (const float*)d_in[1];
    const float* W2     = (const float*)d_in[2];
    const float* b2     = (const float*)d_in[3];
    const float* Wp     = (const float*)d_in[4];
    const float* bp     = (const float*)d_in[5];
    const int*   lab    = (const int*)d_in[6];
    const int*   pidx   = (const int*)d_in[7];
    float* outp = (float*)d_out;
    float* wsf  = (float*)d_ws;

    // zero count + c' + g' accumulators (harness does not re-poison between replays)
    hipMemsetAsync(d_ws, 0, (WS_G + LL * DD) * sizeof(float), stream);

    k_prep<<<NN / 256, 256, 0, stream>>>(matrix, pidx,
                                         (int*)(wsf + WS_CNT), (int*)(wsf + WS_NBR));
    k_deg<<<8192, 256, 0, stream>>>(matrix, (const int*)(wsf + WS_CNT),
                                    (const int*)(wsf + WS_NBR), wsf + WS_QV);
    k_agg<<<256, 256, 0, stream>>>(xf, lab, (const int*)(wsf + WS_CNT),
                                   (const int*)(wsf + WS_NBR), wsf + WS_QV,
                                   wsf + WS_G, wsf + WS_C);
    k_final<<<1, 512, 0, stream>>>(xf, W2, b2, Wp, bp, pidx,
                                   (const int*)(wsf + WS_CNT),
                                   wsf + WS_G, wsf + WS_C, outp);
}

// Round 3
// 159.836 us; speedup vs baseline: 1.3534x; 1.0799x over previous
//
#include <hip/hip_runtime.h>

#define NN 16384
#define DD 512
#define HH 64
#define LL 7

// ws layout (floats):
// [0]            count (int)
// [8..15)        c'[7]   (atomic accum, excludes rsqrt(S))
// [16..3600)     g'[7*512] (atomic accum, excludes rsqrt(S))
// [4096..20480)  nbr[N] (int, compacted neighbor col indices, ascending)
// [20480..36864) qv[N]  (float, rsqrt(deg) per compact slot)
#define WS_CNT  0
#define WS_C    8
#define WS_G    16
#define WS_NBR  4096
#define WS_QV   20480

// Kernel 1 (1 block, 1024 threads): compaction via block prefix-scan (no atomics),
// zero g'/c', seed out = bp.
__global__ void k_prep(const float* __restrict__ matrix,
                       const int* __restrict__ pidx,
                       const float* __restrict__ bp,
                       int* __restrict__ count,
                       int* __restrict__ nbr,
                       float* __restrict__ g,
                       float* __restrict__ c,
                       float* __restrict__ out) {
    __shared__ int lds_wt[16];
    __shared__ int lds_woff[16];
    int t = threadIdx.x;
    int lane = t & 63;
    int wid = t >> 6;

    // zero accumulators
    for (int i = t; i < LL * DD; i += 1024) g[i] = 0.f;
    if (t < LL) { c[t] = 0.f; out[t] = bp[t]; }

    // read 16 cols per thread
    int idx = *pidx;
    const float4* r4 = (const float4*)(matrix + (size_t)idx * NN);
    float4 v[4];
    #pragma unroll
    for (int q = 0; q < 4; ++q) v[q] = r4[t * 4 + q];

    unsigned m16 = 0;
    int cnt_t = 0;
    #pragma unroll
    for (int q = 0; q < 4; ++q) {
        const float* f = &v[q].x;
        #pragma unroll
        for (int cc = 0; cc < 4; ++cc)
            if (f[cc] != 0.f) { m16 |= 1u << (q * 4 + cc); ++cnt_t; }
    }

    // inclusive scan within wave
    int inc = cnt_t;
    #pragma unroll
    for (int off = 1; off < 64; off <<= 1) {
        int u = __shfl_up(inc, off);
        if (lane >= off) inc += u;
    }
    if (lane == 63) lds_wt[wid] = inc;
    __syncthreads();
    if (t == 0) {
        int run = 0;
        #pragma unroll
        for (int w = 0; w < 16; ++w) { int x = lds_wt[w]; lds_woff[w] = run; run += x; }
        *count = run;
    }
    __syncthreads();

    int offb = lds_woff[wid] + inc - cnt_t;  // exclusive offset for this thread
    int w = 0;
    #pragma unroll
    for (int bit = 0; bit < 16; ++bit) {
        if (m16 & (1u << bit)) nbr[offb + (w++)] = t * 16 + bit;
    }
}

// Kernel 2: per compacted neighbor row j, qv[i] = rsqrt(deg_j). Dense blocks.
__global__ void k_deg(const float* __restrict__ matrix,
                      const int* __restrict__ count,
                      const int* __restrict__ nbr,
                      float* __restrict__ qv) {
    __shared__ float sdata[4];
    int t = threadIdx.x;
    int lane = t & 63;
    int wid = t >> 6;
    int cnt = *count;
    for (int i = blockIdx.x; i < cnt; i += gridDim.x) {
        int j = nbr[i];
        const float4* r4 = (const float4*)(matrix + (size_t)j * NN);
        float v0 = 0.f, v1 = 0.f, v2 = 0.f, v3 = 0.f;
        #pragma unroll
        for (int it = 0; it < 4; ++it) {
            float4 a  = r4[t + (it * 4 + 0) * 256];
            float4 b  = r4[t + (it * 4 + 1) * 256];
            float4 cc = r4[t + (it * 4 + 2) * 256];
            float4 d  = r4[t + (it * 4 + 3) * 256];
            v0 += a.x + a.y + a.z + a.w;
            v1 += b.x + b.y + b.z + b.w;
            v2 += cc.x + cc.y + cc.z + cc.w;
            v3 += d.x + d.y + d.z + d.w;
        }
        float v = (v0 + v1) + (v2 + v3);
        #pragma unroll
        for (int off = 32; off > 0; off >>= 1)
            v += __shfl_down(v, off);
        if (lane == 0) sdata[wid] = v;
        __syncthreads();
        if (t == 0) {
            float deg = (sdata[0] + sdata[1]) + (sdata[2] + sdata[3]);
            qv[i] = rsqrtf(deg);
        }
        __syncthreads();
    }
}

// Kernel 3: g'[l][d] = sum_i q_i*lab[j_i][l]*xf[j_i][d]; c'[l] = sum_i q_i*lab[j_i][l]
// 4 independent i-chains per loop trip for MLP.
__global__ void k_agg(const float* __restrict__ xf,
                      const int* __restrict__ lab,
                      const int* __restrict__ count,
                      const int* __restrict__ nbr,
                      const float* __restrict__ qv,
                      float* __restrict__ g,
                      float* __restrict__ c) {
    int t = threadIdx.x;  // 256 threads, each owns 2 feature dims
    int d0 = t * 2;
    int cnt = *count;
    float2 acc[LL];
    #pragma unroll
    for (int l = 0; l < LL; ++l) acc[l] = make_float2(0.f, 0.f);
    float cacc[LL] = {0.f, 0.f, 0.f, 0.f, 0.f, 0.f, 0.f};

    for (int base = 0; base < cnt; base += 1024) {
        int ii[4];
        bool act[4];
        int jj[4];
        float qq[4];
        float2 xv[4];
        #pragma unroll
        for (int k = 0; k < 4; ++k) {
            ii[k] = base + blockIdx.x + k * 256;
            act[k] = ii[k] < cnt;
        }
        #pragma unroll
        for (int k = 0; k < 4; ++k) {
            jj[k] = act[k] ? nbr[ii[k]] : 0;
            qq[k] = act[k] ? qv[ii[k]] : 0.f;
        }
        #pragma unroll
        for (int k = 0; k < 4; ++k)
            xv[k] = act[k] ? *(const float2*)(xf + (size_t)jj[k] * DD + d0)
                           : make_float2(0.f, 0.f);
        #pragma unroll
        for (int k = 0; k < 4; ++k) {
            float wl[LL];
            #pragma unroll
            for (int l = 0; l < LL; ++l)
                wl[l] = qq[k] * (float)lab[jj[k] * LL + l];
            #pragma unroll
            for (int l = 0; l < LL; ++l) {
                acc[l].x = fmaf(wl[l], xv[k].x, acc[l].x);
                acc[l].y = fmaf(wl[l], xv[k].y, acc[l].y);
            }
            if (t == 0) {
                #pragma unroll
                for (int l = 0; l < LL; ++l) cacc[l] += wl[l];
            }
        }
    }
    #pragma unroll
    for (int l = 0; l < LL; ++l) {
        atomicAdd(&g[l * DD + d0],     acc[l].x);
        atomicAdd(&g[l * DD + d0 + 1], acc[l].y);
    }
    if (t == 0) {
        #pragma unroll
        for (int l = 0; l < LL; ++l) atomicAdd(&c[l], cacc[l]);
    }
}

// Kernel 4 (8 blocks, 256 threads): 4 threads per concat position.
// val -> relu -> max(xf[index]) -> partial @Wp atomics into out (pre-seeded with bp).
__global__ void k_final(const float* __restrict__ xf,
                        const float* __restrict__ W2,
                        const float* __restrict__ b2,
                        const float* __restrict__ Wp,
                        const int* __restrict__ pidx,
                        const int* __restrict__ count,
                        const float* __restrict__ g,
                        const float* __restrict__ c,
                        float* __restrict__ out) {
    __shared__ float out_acc[LL];
    int t = threadIdx.x;
    int p = blockIdx.x * 64 + (t >> 2);   // concat position [0,512)
    int sub = t & 3;                      // d-chunk [sub*128, sub*128+128)
    int idx = *pidx;
    float sc = rsqrtf((float)(*count));

    const float* src;
    float bias;
    int h;
    if (p < HH) {
        src = xf + (size_t)idx * DD;
        h = p;
        bias = b2[p];
    } else {
        int l = (p - HH) >> 6;
        h = (p - HH) & 63;
        src = g + l * DD;
        bias = c[l] * b2[h];
    }
    float s0 = 0.f, s1 = 0.f, s2 = 0.f, s3 = 0.f;
    int dbase = sub * 128;
    #pragma unroll 8
    for (int d = 0; d < 128; d += 4) {
        s0 = fmaf(src[dbase + d],     W2[(dbase + d)     * HH + h], s0);
        s1 = fmaf(src[dbase + d + 1], W2[(dbase + d + 1) * HH + h], s1);
        s2 = fmaf(src[dbase + d + 2], W2[(dbase + d + 2) * HH + h], s2);
        s3 = fmaf(src[dbase + d + 3], W2[(dbase + d + 3) * HH + h], s3);
    }
    float v = (s0 + s1) + (s2 + s3);
    v += __shfl_down(v, 2);
    v += __shfl_down(v, 1);

    if (t < LL) out_acc[t] = 0.f;
    __syncthreads();

    if (sub == 0) {
        float val = v + bias;
        if (p >= HH) val *= sc;
        float relu_v = val > 0.f ? val : 0.f;
        float hc = fmaxf(xf[(size_t)idx * DD + p], relu_v);
        #pragma unroll
        for (int o = 0; o < LL; ++o)
            atomicAdd(&out_acc[o], hc * Wp[p * LL + o]);
    }
    __syncthreads();
    if (t < LL) atomicAdd(&out[t], out_acc[t]);
}

extern "C" void kernel_launch(void* const* d_in, const int* in_sizes, int n_in,
                              void* d_out, int out_size, void* d_ws, size_t ws_size,
                              hipStream_t stream) {
    const float* matrix = (const float*)d_in[0];
    const float* xf     = (const float*)d_in[1];
    const float* W2     = (const float*)d_in[2];
    const float* b2     = (const float*)d_in[3];
    const float* Wp     = (const float*)d_in[4];
    const float* bp     = (const float*)d_in[5];
    const int*   lab    = (const int*)d_in[6];
    const int*   pidx   = (const int*)d_in[7];
    float* outp = (float*)d_out;
    float* wsf  = (float*)d_ws;

    k_prep<<<1, 1024, 0, stream>>>(matrix, pidx, bp,
                                   (int*)(wsf + WS_CNT), (int*)(wsf + WS_NBR),
                                   wsf + WS_G, wsf + WS_C, outp);
    k_deg<<<8192, 256, 0, stream>>>(matrix, (const int*)(wsf + WS_CNT),
                                    (const int*)(wsf + WS_NBR), wsf + WS_QV);
    k_agg<<<256, 256, 0, stream>>>(xf, lab, (const int*)(wsf + WS_CNT),
                                   (const int*)(wsf + WS_NBR), wsf + WS_QV,
                                   wsf + WS_G, wsf + WS_C);
    k_final<<<8, 256, 0, stream>>>(xf, W2, b2, Wp, pidx,
                                   (const int*)(wsf + WS_CNT),
                                   wsf + WS_G, wsf + WS_C, outp);
}

// Round 5
// 135.362 us; speedup vs baseline: 1.5981x; 1.1808x over previous
//
#include <hip/hip_runtime.h>

#define NN 16384
#define DD 512
#define HH 64
#define LL 7
#define NAGG 256           // agg blocks (= partial copies)
#define JPB  (NN / NAGG)   // 64 j's per agg block

typedef float f32x4 __attribute__((ext_vector_type(4)));

// ws floats layout (all regions fully overwritten every replay — no init needed):
// [0 .. 16384)                  qv[NN]        (rsqrt(deg_j) for neighbors, else 0)
// [16384]                       S (float)
// [16400 .. 16400+NAGG*8)       cpart[NAGG][8]
// [20480 .. 20480+NAGG*7*512)   gpart[NAGG][7][512]   (~3.6 MB)
#define WS_QV 0
#define WS_S  16384
#define WS_CP 16400
#define WS_GP 20480

// Kernel 1: self-selecting per-row degree. Block j: gate on matrix[index][j].
__global__ void k_deg(const float* __restrict__ matrix,
                      const int* __restrict__ pidx,
                      float* __restrict__ qv) {
    __shared__ float sdata[4];
    int j = blockIdx.x;
    int t = threadIdx.x;
    int lane = t & 63;
    int wid = t >> 6;
    int idx = *pidx;
    float m = matrix[(size_t)idx * NN + j];   // broadcast, L2-hot after warmup
    if (m == 0.f) {
        if (t == 0) qv[j] = 0.f;
        return;
    }
    const f32x4* r4 = (const f32x4*)(matrix + (size_t)j * NN);
    float v0 = 0.f, v1 = 0.f, v2 = 0.f, v3 = 0.f;
    #pragma unroll
    for (int it = 0; it < 4; ++it) {
        f32x4 a  = __builtin_nontemporal_load(&r4[t + (it * 4 + 0) * 256]);
        f32x4 b  = __builtin_nontemporal_load(&r4[t + (it * 4 + 1) * 256]);
        f32x4 cc = __builtin_nontemporal_load(&r4[t + (it * 4 + 2) * 256]);
        f32x4 d  = __builtin_nontemporal_load(&r4[t + (it * 4 + 3) * 256]);
        v0 += a.x + a.y + a.z + a.w;
        v1 += b.x + b.y + b.z + b.w;
        v2 += cc.x + cc.y + cc.z + cc.w;
        v3 += d.x + d.y + d.z + d.w;
    }
    float v = (v0 + v1) + (v2 + v3);
    #pragma unroll
    for (int off = 32; off > 0; off >>= 1)
        v += __shfl_down(v, off);
    if (lane == 0) sdata[wid] = v;
    __syncthreads();
    if (t == 0) {
        float deg = (sdata[0] + sdata[1]) + (sdata[2] + sdata[3]);
        qv[j] = rsqrtf(deg);
    }
}

// Kernel 2: per-block partial g'[l][d] / c'[l] over dense affine j (uniform gating).
// Stores partials (no atomics). Block 0 also computes S and seeds out = bp.
__global__ void k_agg(const float* __restrict__ matrix,
                      const float* __restrict__ xf,
                      const int* __restrict__ lab,
                      const int* __restrict__ pidx,
                      const float* __restrict__ bp,
                      const float* __restrict__ qv,
                      float* __restrict__ gpart,
                      float* __restrict__ cpart,
                      float* __restrict__ Sout,
                      float* __restrict__ out) {
    __shared__ float sS[4];
    int t = threadIdx.x;            // 256, each owns 2 feature dims
    int b = blockIdx.x;
    int d0 = t * 2;
    float2 acc[LL];
    #pragma unroll
    for (int l = 0; l < LL; ++l) acc[l] = make_float2(0.f, 0.f);
    float cacc[LL] = {0.f, 0.f, 0.f, 0.f, 0.f, 0.f, 0.f};

    #pragma unroll 1
    for (int trip = 0; trip < JPB / 4; ++trip) {      // 16 trips, 4-deep
        int jj[4];
        float qq[4];
        #pragma unroll
        for (int k = 0; k < 4; ++k) {
            jj[k] = b + (trip * 4 + k) * NAGG;
            qq[k] = qv[jj[k]];                         // uniform broadcast load
        }
        #pragma unroll
        for (int k = 0; k < 4; ++k) {
            if (qq[k] != 0.f) {                        // block-uniform branch
                float2 xv = *(const float2*)(xf + (size_t)jj[k] * DD + d0);
                float wl[LL];
                #pragma unroll
                for (int l = 0; l < LL; ++l)
                    wl[l] = qq[k] * (float)lab[jj[k] * LL + l];
                #pragma unroll
                for (int l = 0; l < LL; ++l) {
                    acc[l].x = fmaf(wl[l], xv.x, acc[l].x);
                    acc[l].y = fmaf(wl[l], xv.y, acc[l].y);
                }
                #pragma unroll
                for (int l = 0; l < LL; ++l) cacc[l] += wl[l];
            }
        }
    }
    // store partials (streaming, no atomics)
    #pragma unroll
    for (int l = 0; l < LL; ++l)
        *(float2*)(gpart + ((size_t)b * LL + l) * DD + d0) = acc[l];
    if (t == 0) {
        #pragma unroll
        for (int l = 0; l < LL; ++l) cpart[b * 8 + l] = cacc[l];  // block-uniform value
    }
    if (b == 0) {
        // S = sum(matrix[index,:]) — row is L2-hot from k_deg's gate loads
        int idx = *pidx;
        const f32x4* r4 = (const f32x4*)(matrix + (size_t)idx * NN);
        float v = 0.f;
        #pragma unroll
        for (int it = 0; it < 16; ++it) {
            f32x4 a = r4[t + it * 256];
            v += a.x + a.y + a.z + a.w;
        }
        #pragma unroll
        for (int off = 32; off > 0; off >>= 1)
            v += __shfl_down(v, off);
        if ((t & 63) == 0) sS[t >> 6] = v;
        __syncthreads();
        if (t == 0) {
            Sout[0] = (sS[0] + sS[1]) + (sS[2] + sS[3]);
            #pragma unroll
            for (int l = 0; l < LL; ++l) out[l] = bp[l];   // seed output
        }
    }
}

// Kernel 3 (8 blocks, 256 threads): block 0 -> z[index] part (p<64);
// block b>=1 -> l=b-1: reduce 256 partial copies into LDS, dot from LDS.
__global__ void k_final(const float* __restrict__ xf,
                        const float* __restrict__ W2,
                        const float* __restrict__ b2,
                        const float* __restrict__ Wp,
                        const int* __restrict__ pidx,
                        const float* __restrict__ gpart,
                        const float* __restrict__ cpart,
                        const float* __restrict__ Sf,
                        float* __restrict__ out) {
    __shared__ float gl[DD];
    __shared__ float csd[4];
    __shared__ float csum_s;
    __shared__ float out_acc[LL];
    int t = threadIdx.x;
    int b = blockIdx.x;
    int lane = t & 63;
    int wid = t >> 6;
    int idx = *pidx;

    if (b >= 1) {
        int l = b - 1;
        float2 s = make_float2(0.f, 0.f);
        const float* gbase = gpart + (size_t)l * DD + t * 2;
        #pragma unroll 8
        for (int pb = 0; pb < NAGG; ++pb) {
            float2 v = *(const float2*)(gbase + (size_t)pb * (LL * DD));
            s.x += v.x; s.y += v.y;
        }
        gl[t * 2] = s.x;
        gl[t * 2 + 1] = s.y;
        float cv = cpart[t * 8 + l];
        #pragma unroll
        for (int off = 32; off > 0; off >>= 1)
            cv += __shfl_down(cv, off);
        if (lane == 0) csd[wid] = cv;
    }
    if (t < LL) out_acc[t] = 0.f;
    __syncthreads();
    if (b >= 1 && t == 0)
        csum_s = (csd[0] + csd[1]) + (csd[2] + csd[3]);
    __syncthreads();

    int p = b * 64 + (t >> 2);    // concat position
    int sub = t & 3;              // d-chunk
    int h = (b == 0) ? p : (p - HH) & 63;
    int dbase = sub * 128;
    const float* src = (b == 0) ? (xf + (size_t)idx * DD) : gl;
    float s0 = 0.f, s1 = 0.f, s2 = 0.f, s3 = 0.f;
    #pragma unroll 8
    for (int d = 0; d < 128; d += 4) {
        s0 = fmaf(src[dbase + d],     W2[(dbase + d)     * HH + h], s0);
        s1 = fmaf(src[dbase + d + 1], W2[(dbase + d + 1) * HH + h], s1);
        s2 = fmaf(src[dbase + d + 2], W2[(dbase + d + 2) * HH + h], s2);
        s3 = fmaf(src[dbase + d + 3], W2[(dbase + d + 3) * HH + h], s3);
    }
    float v = (s0 + s1) + (s2 + s3);
    v += __shfl_down(v, 2);
    v += __shfl_down(v, 1);

    if (sub == 0) {
        float val;
        if (b == 0) {
            val = v + b2[p];
        } else {
            float sc = rsqrtf(Sf[0]);
            val = (v + csum_s * b2[h]) * sc;
        }
        float relu_v = val > 0.f ? val : 0.f;
        float hc = fmaxf(xf[(size_t)idx * DD + p], relu_v);
        #pragma unroll
        for (int o = 0; o < LL; ++o)
            atomicAdd(&out_acc[o], hc * Wp[p * LL + o]);
    }
    __syncthreads();
    if (t < LL) atomicAdd(&out[t], out_acc[t]);
}

extern "C" void kernel_launch(void* const* d_in, const int* in_sizes, int n_in,
                              void* d_out, int out_size, void* d_ws, size_t ws_size,
                              hipStream_t stream) {
    const float* matrix = (const float*)d_in[0];
    const float* xf     = (const float*)d_in[1];
    const float* W2     = (const float*)d_in[2];
    const float* b2     = (const float*)d_in[3];
    const float* Wp     = (const float*)d_in[4];
    const float* bp     = (const float*)d_in[5];
    const int*   lab    = (const int*)d_in[6];
    const int*   pidx   = (const int*)d_in[7];
    float* outp = (float*)d_out;
    float* wsf  = (float*)d_ws;

    k_deg<<<NN, 256, 0, stream>>>(matrix, pidx, wsf + WS_QV);
    k_agg<<<NAGG, 256, 0, stream>>>(matrix, xf, lab, pidx, bp, wsf + WS_QV,
                                    wsf + WS_GP, wsf + WS_CP, wsf + WS_S, outp);
    k_final<<<8, 256, 0, stream>>>(xf, W2, b2, Wp, pidx,
                                   wsf + WS_GP, wsf + WS_CP, wsf + WS_S, outp);
}

// Round 6
// 134.430 us; speedup vs baseline: 1.6092x; 1.0069x over previous
//
#include <hip/hip_runtime.h>

#define NN 16384
#define DD 512
#define HH 64
#define LL 7
#define NAGG 256           // agg blocks (= partial copies)
#define JPB  (NN / NAGG)   // 64 j's per agg block
#define DEGB 4096          // deg blocks
#define RPB  (NN / DEGB)   // 4 rows per deg block

typedef float f32x4 __attribute__((ext_vector_type(4)));

// ws floats layout (all regions fully overwritten every replay — no init needed):
// [0 .. 16384)                  qv[NN]        (rsqrt(deg_j) for neighbors, else 0)
// [16384]                       S (float)
// [16400 .. 16400+NAGG*8)       cpart[NAGG][8]
// [20480 .. 20480+NAGG*7*512)   gpart[NAGG][7][512]   (~3.6 MB)
#define WS_QV 0
#define WS_S  16384
#define WS_CP 16400
#define WS_GP 20480

// Kernel 1: 4096 blocks x 4 rows. Gates loaded up-front; active rows streamed
// back-to-back with no inter-row barrier; one reduce phase at the end.
__global__ void k_deg(const float* __restrict__ matrix,
                      const int* __restrict__ pidx,
                      float* __restrict__ qv) {
    __shared__ float sdata[RPB][4];
    int t = threadIdx.x;
    int lane = t & 63;
    int wid = t >> 6;
    int idx = *pidx;
    int j0 = blockIdx.x;

    float gate[RPB];
    #pragma unroll
    for (int k = 0; k < RPB; ++k)
        gate[k] = matrix[(size_t)idx * NN + j0 + k * DEGB];   // broadcast, L2-hot

    float vsum[RPB];
    #pragma unroll
    for (int k = 0; k < RPB; ++k) vsum[k] = 0.f;

    #pragma unroll
    for (int k = 0; k < RPB; ++k) {
        if (gate[k] != 0.f) {                       // block-uniform branch
            const f32x4* r4 = (const f32x4*)(matrix + (size_t)(j0 + k * DEGB) * NN);
            float v0 = 0.f, v1 = 0.f, v2 = 0.f, v3 = 0.f;
            #pragma unroll
            for (int it = 0; it < 4; ++it) {
                f32x4 a  = __builtin_nontemporal_load(&r4[t + (it * 4 + 0) * 256]);
                f32x4 b  = __builtin_nontemporal_load(&r4[t + (it * 4 + 1) * 256]);
                f32x4 cc = __builtin_nontemporal_load(&r4[t + (it * 4 + 2) * 256]);
                f32x4 d  = __builtin_nontemporal_load(&r4[t + (it * 4 + 3) * 256]);
                v0 += a.x + a.y + a.z + a.w;
                v1 += b.x + b.y + b.z + b.w;
                v2 += cc.x + cc.y + cc.z + cc.w;
                v3 += d.x + d.y + d.z + d.w;
            }
            vsum[k] = (v0 + v1) + (v2 + v3);
        }
    }

    #pragma unroll
    for (int k = 0; k < RPB; ++k) {
        float v = vsum[k];
        #pragma unroll
        for (int off = 32; off > 0; off >>= 1)
            v += __shfl_down(v, off);
        if (lane == 0) sdata[k][wid] = v;
    }
    __syncthreads();
    if (t < RPB) {
        float deg = (sdata[t][0] + sdata[t][1]) + (sdata[t][2] + sdata[t][3]);
        qv[j0 + t * DEGB] = deg > 0.f ? rsqrtf(deg) : 0.f;   // deg==0 <=> inactive
    }
}

// Kernel 2: per-block partial g'[l][d] / c'[l] over dense affine j, 8-deep ILP.
// Stores partials (no atomics). Block 0 also computes S and seeds out = bp.
__global__ void k_agg(const float* __restrict__ matrix,
                      const float* __restrict__ xf,
                      const int* __restrict__ lab,
                      const int* __restrict__ pidx,
                      const float* __restrict__ bp,
                      const float* __restrict__ qv,
                      float* __restrict__ gpart,
                      float* __restrict__ cpart,
                      float* __restrict__ Sout,
                      float* __restrict__ out) {
    __shared__ float sS[4];
    int t = threadIdx.x;            // 256, each owns 2 feature dims
    int b = blockIdx.x;
    int d0 = t * 2;
    float2 acc[LL];
    #pragma unroll
    for (int l = 0; l < LL; ++l) acc[l] = make_float2(0.f, 0.f);
    float cacc[LL] = {0.f, 0.f, 0.f, 0.f, 0.f, 0.f, 0.f};

    #pragma unroll 1
    for (int trip = 0; trip < JPB / 8; ++trip) {      // 8 trips, 8-deep
        int jj[8];
        float qq[8];
        #pragma unroll
        for (int k = 0; k < 8; ++k) {
            jj[k] = b + (trip * 8 + k) * NAGG;
            qq[k] = qv[jj[k]];                         // uniform broadcast load
        }
        #pragma unroll
        for (int k = 0; k < 8; ++k) {
            if (qq[k] != 0.f) {                        // block-uniform branch
                float2 xv = *(const float2*)(xf + (size_t)jj[k] * DD + d0);
                float wl[LL];
                #pragma unroll
                for (int l = 0; l < LL; ++l)
                    wl[l] = qq[k] * (float)lab[jj[k] * LL + l];
                #pragma unroll
                for (int l = 0; l < LL; ++l) {
                    acc[l].x = fmaf(wl[l], xv.x, acc[l].x);
                    acc[l].y = fmaf(wl[l], xv.y, acc[l].y);
                }
                #pragma unroll
                for (int l = 0; l < LL; ++l) cacc[l] += wl[l];
            }
        }
    }
    // store partials (streaming, no atomics)
    #pragma unroll
    for (int l = 0; l < LL; ++l)
        *(float2*)(gpart + ((size_t)b * LL + l) * DD + d0) = acc[l];
    if (t == 0) {
        #pragma unroll
        for (int l = 0; l < LL; ++l) cpart[b * 8 + l] = cacc[l];  // block-uniform value
    }
    if (b == 0) {
        // S = sum(matrix[index,:]) — row is L2-hot from k_deg's gate loads
        int idx = *pidx;
        const f32x4* r4 = (const f32x4*)(matrix + (size_t)idx * NN);
        float v = 0.f;
        #pragma unroll
        for (int it = 0; it < 16; ++it) {
            f32x4 a = r4[t + it * 256];
            v += a.x + a.y + a.z + a.w;
        }
        #pragma unroll
        for (int off = 32; off > 0; off >>= 1)
            v += __shfl_down(v, off);
        if ((t & 63) == 0) sS[t >> 6] = v;
        __syncthreads();
        if (t == 0) {
            Sout[0] = (sS[0] + sS[1]) + (sS[2] + sS[3]);
            #pragma unroll
            for (int l = 0; l < LL; ++l) out[l] = bp[l];   // seed output
        }
    }
}

// Kernel 3 (8 blocks, 256 threads): block 0 -> z[index] part (p<64);
// block b>=1 -> l=b-1: reduce 256 partial copies (split across 4 waves,
// independent loads) into LDS, dot from LDS.
__global__ void k_final(const float* __restrict__ xf,
                        const float* __restrict__ W2,
                        const float* __restrict__ b2,
                        const float* __restrict__ Wp,
                        const int* __restrict__ pidx,
                        const float* __restrict__ gpart,
                        const float* __restrict__ cpart,
                        const float* __restrict__ Sf,
                        float* __restrict__ out) {
    __shared__ float glp[4][DD];   // per-wave partials
    __shared__ float gl[DD];
    __shared__ float csd[4];
    __shared__ float csum_s;
    __shared__ float out_acc[LL];
    int t = threadIdx.x;
    int b = blockIdx.x;
    int lane = t & 63;
    int wid = t >> 6;
    int idx = *pidx;

    // phase A: wave-split partial reduce + csum partials
    if (b >= 1) {
        int l = b - 1;
        float2 s[4];
        #pragma unroll
        for (int q = 0; q < 4; ++q) s[q] = make_float2(0.f, 0.f);
        #pragma unroll 4
        for (int pbi = 0; pbi < NAGG / 4; ++pbi) {
            int pb = wid * (NAGG / 4) + pbi;
            const float* gb = gpart + ((size_t)pb * LL + l) * DD;
            #pragma unroll
            for (int q = 0; q < 4; ++q) {
                float2 v = *(const float2*)(gb + (lane + q * 64) * 2);
                s[q].x += v.x; s[q].y += v.y;
            }
        }
        #pragma unroll
        for (int q = 0; q < 4; ++q) {
            glp[wid][(lane + q * 64) * 2]     = s[q].x;
            glp[wid][(lane + q * 64) * 2 + 1] = s[q].y;
        }
        float cv = cpart[t * 8 + l];
        #pragma unroll
        for (int off = 32; off > 0; off >>= 1)
            cv += __shfl_down(cv, off);
        if (lane == 0) csd[wid] = cv;
    }
    if (t < LL) out_acc[t] = 0.f;
    __syncthreads();

    // phase B: combine wave partials
    if (b >= 1) {
        gl[t * 2]     = ((glp[0][t * 2]     + glp[1][t * 2])
                       + (glp[2][t * 2]     + glp[3][t * 2]));
        gl[t * 2 + 1] = ((glp[0][t * 2 + 1] + glp[1][t * 2 + 1])
                       + (glp[2][t * 2 + 1] + glp[3][t * 2 + 1]));
        if (t == 0) csum_s = (csd[0] + csd[1]) + (csd[2] + csd[3]);
    }
    __syncthreads();

    // phase C: dot products
    int p = b * 64 + (t >> 2);    // concat position
    int sub = t & 3;              // d-chunk
    int h = (b == 0) ? p : (p - HH) & 63;
    int dbase = sub * 128;
    const float* src = (b == 0) ? (xf + (size_t)idx * DD) : gl;
    float s0 = 0.f, s1 = 0.f, s2 = 0.f, s3 = 0.f;
    #pragma unroll 8
    for (int d = 0; d < 128; d += 4) {
        s0 = fmaf(src[dbase + d],     W2[(dbase + d)     * HH + h], s0);
        s1 = fmaf(src[dbase + d + 1], W2[(dbase + d + 1) * HH + h], s1);
        s2 = fmaf(src[dbase + d + 2], W2[(dbase + d + 2) * HH + h], s2);
        s3 = fmaf(src[dbase + d + 3], W2[(dbase + d + 3) * HH + h], s3);
    }
    float v = (s0 + s1) + (s2 + s3);
    v += __shfl_down(v, 2);
    v += __shfl_down(v, 1);

    if (sub == 0) {
        float val;
        if (b == 0) {
            val = v + b2[p];
        } else {
            float sc = rsqrtf(Sf[0]);
            val = (v + csum_s * b2[h]) * sc;
        }
        float relu_v = val > 0.f ? val : 0.f;
        float hc = fmaxf(xf[(size_t)idx * DD + p], relu_v);
        #pragma unroll
        for (int o = 0; o < LL; ++o)
            atomicAdd(&out_acc[o], hc * Wp[p * LL + o]);
    }
    __syncthreads();
    if (t < LL) atomicAdd(&out[t], out_acc[t]);
}

extern "C" void kernel_launch(void* const* d_in, const int* in_sizes, int n_in,
                              void* d_out, int out_size, void* d_ws, size_t ws_size,
                              hipStream_t stream) {
    const float* matrix = (const float*)d_in[0];
    const float* xf     = (const float*)d_in[1];
    const float* W2     = (const float*)d_in[2];
    const float* b2     = (const float*)d_in[3];
    const float* Wp     = (const float*)d_in[4];
    const float* bp     = (const float*)d_in[5];
    const int*   lab    = (const int*)d_in[6];
    const int*   pidx   = (const int*)d_in[7];
    float* outp = (float*)d_out;
    float* wsf  = (float*)d_ws;

    k_deg<<<DEGB, 256, 0, stream>>>(matrix, pidx, wsf + WS_QV);
    k_agg<<<NAGG, 256, 0, stream>>>(matrix, xf, lab, pidx, bp, wsf + WS_QV,
                                    wsf + WS_GP, wsf + WS_CP, wsf + WS_S, outp);
    k_final<<<8, 256, 0, stream>>>(xf, W2, b2, Wp, pidx,
                                   wsf + WS_GP, wsf + WS_CP, wsf + WS_S, outp);
}